// Round 18
// baseline (147.976 us; speedup 1.0000x reference)
//
#include <hip/hip_runtime.h>
#include <hip/hip_bf16.h>
#include <hip/hip_fp16.h>

// ---------------- problem constants ----------------
#define N_VEC   16384      // 16*32*32 latent vectors
#define K_CODES 8192
#define D_DIM   256
#define NSPLIT  8          // code-dim splits (grid.y)
#define KT_PER  8          // 1024 cols per split / 128 per kt
#define BM      128

// d_out layout (float32 elements)
#define ZQ_SIZE  (16*256*32*32)          // 4194304
#define DIFF_OFF ZQ_SIZE
#define IDX_OFF  (ZQ_SIZE + 1)
#define PERP_OFF (ZQ_SIZE + 1 + N_VEC)

// ws layout (bytes); ~14.6 MB
#define WS_ENORM 0
#define WS_ZH    65536
#define WS_EH    (WS_ZH + N_VEC * D_DIM * 2)      // +8 MB
#define WS_P2    (WS_EH + K_CODES * D_DIM * 2)    // +4 MB
#define WS_IDXI  (WS_P2 + NSPLIT * N_VEC * 16)    // +2 MB
#define WS_LOSS  (WS_IDXI + N_VEC * 4)            // 4096 floats

typedef _Float16 f16x4 __attribute__((ext_vector_type(4)));
typedef float    f32x4 __attribute__((ext_vector_type(4)));

// monotone (score, idx) 64-bit key: smaller key = smaller score, tie -> smaller idx
__device__ __forceinline__ unsigned long long skey(float s, int c) {
    unsigned u = __float_as_uint(s);
    u ^= (unsigned)((int)u >> 31) | 0x80000000u;
    return ((unsigned long long)u << 13) | (unsigned)c;
}

// Z (A-operand) 16 KB tile: (row 0..127, dloc 0..63 f16), slot = (dloc>>3) ^ (row&7)
__device__ __forceinline__ int swz_off(int row, int dloc) {
    return row * 128 + ((((dloc >> 3) ^ (row & 7))) << 4) + ((dloc & 7) << 1);
}

__device__ __forceinline__ void gload16(const void* g, void* l) {
    __builtin_amdgcn_global_load_lds((const __attribute__((address_space(1))) unsigned int*)g,
                                     (__attribute__((address_space(3))) unsigned int*)l,
                                     16, 0, 0);
}

#define VMW__(n) asm volatile("s_waitcnt vmcnt(" #n ")" ::: "memory")
#define VMW(n) VMW__(n)

// ---------------- kernel 0: fp32 -> fp16 pre-tiled+swizzled, fused codebook norms ----------------
// Z: 16 KB tiles (128 rows x 64 d), slot = (dloc>>3) ^ (row&7)   [unchanged]
// E: 4 KB chunks (128 cols x 16 d): byte = col*32 + ((q ^ ((col>>2)&3)) << 3), q = d-quad
//    -> conflict-free b64 reads (banks enumerated distinct for all 16 lanes/group)
__global__ __launch_bounds__(256) void convert_kernel(const float* __restrict__ Z,
                                                      const float* __restrict__ E,
                                                      char* __restrict__ ws) {
    const int t  = threadIdx.x;
    const int r  = blockIdx.x * 4 + (t >> 6);   // one wave per row
    const int d0 = (t & 63) * 4;
    const float* src;
    char* dh;
    const bool isE = (r >= N_VEC);
    if (!isE) {
        src = Z + (size_t)r * D_DIM;
        const int rowl = r & 127;
        dh = ws + WS_ZH + (size_t)(((r >> 7) * 4) + (d0 >> 6)) * 16384
           + swz_off(rowl, d0 & 63);
    } else {
        const int re = r - N_VEC;
        src = E + (size_t)re * D_DIM;
        const int col = re & 127;
        const int q   = (d0 >> 2) & 3;
        dh = ws + WS_EH + (size_t)((re >> 7) * 16 + (d0 >> 4)) * 4096
           + col * 32 + ((q ^ ((col >> 2) & 3)) << 3);
    }
    const float4 v = *reinterpret_cast<const float4*>(src + d0);
    const unsigned h0 = __half_as_ushort(__float2half(v.x));
    const unsigned h1 = __half_as_ushort(__float2half(v.y));
    const unsigned h2 = __half_as_ushort(__float2half(v.z));
    const unsigned h3 = __half_as_ushort(__float2half(v.w));
    uint2 hi;
    hi.x = h0 | (h1 << 16);  hi.y = h2 | (h3 << 16);
    *reinterpret_cast<uint2*>(dh) = hi;

    if (isE) {   // fused ||e||^2 (fp32, exact same reduction as all passing rounds)
        float s = v.x * v.x + v.y * v.y + v.z * v.z + v.w * v.w;
        #pragma unroll
        for (int off = 32; off; off >>= 1) s += __shfl_down(s, off);
        if ((t & 63) == 0) ((float*)(ws + WS_ENORM))[r - N_VEC] = s;
    }
}

// ---------------- kernel 1: fp16 MFMA screen; A static in LDS (64 KB), B 4-slot ring
//   of 4 KB chunks staged 2 phases ahead -> per-phase wait vmcnt(1) (over-wait-safe:
//   any stray compiler VMEM op is younger than the required stage, vmcnt retires
//   oldest-first), single barrier per phase. 128 phases x K=16 (mfma 16x16x16). ----------------
__global__ __launch_bounds__(256, 2) void vq_mfma_kernel(const char* __restrict__ ws_ro,
                                                         ulonglong2* __restrict__ part2) {
    __shared__ short lds[40960];   // A: [0,32768) shorts (64 KB); ring: [32768,40960) 4x2048

    const int tid  = threadIdx.x;
    const int lane = tid & 63, wid = tid >> 6;
    const int lane15 = lane & 15, g = lane >> 4;
    const int g1 = g >> 1;
    const int wm = wid >> 1, wn = wid & 1;
    const int bx = blockIdx.x, ksp = blockIdx.y;
    const int row0 = bx * BM;
    const int kbase = ksp * (K_CODES / NSPLIT);

    const char* zh = ws_ro + WS_ZH;
    const char* eh = ws_ro + WS_EH;
    const float* enorm = (const float*)(ws_ro + WS_ENORM);
    short* ring = lds + 32768;

    // stage one 4 KB chunk (kt_, pp_): cols [kbase+kt_*128,+128) x d [16*pp_,+16)
    // -> ring slot (pp_)&3 (== global-phase%4); 1 gload16 per thread
    #define STAGE_C(kt_, pp_)                                                          \
    do {                                                                               \
        const char* sC = eh + (size_t)(((ksp * 8 + (kt_)) * 16) + (pp_)) * 4096        \
                            + tid * 16;                                                \
        gload16(sC, ring + ((pp_) & 3) * 2048 + tid * 8);                              \
    } while (0)

    // ---- prologue: A (64 KB linear) + chunks 0,1 ----
    {
        const char* srcA = zh + (size_t)bx * 65536 + wid * 16384 + lane * 16;
        short* dA = lds + wid * 8192 + lane * 8;
        #pragma unroll
        for (int i = 0; i < 16; ++i) gload16(srcA + i * 1024, dA + i * 512);
    }
    STAGE_C(0, 0);
    STAGE_C(0, 1);
    VMW(1);                          // A + chunk0 retired; chunk1 may fly
    __builtin_amdgcn_s_barrier();
    __builtin_amdgcn_sched_barrier(0);

    // loop-invariant fragment terms (shorts)
    int rowbase[4], r7[4];
    #pragma unroll
    for (int m = 0; m < 4; ++m) {
        const int row = wm * 64 + m * 16 + lane15;
        rowbase[m] = row * 64 + 4 * (g & 1);
        r7[m]      = row & 7;
    }
    int boffn[4];
    #pragma unroll
    for (int n = 0; n < 4; ++n) {
        const int col = wn * 64 + n * 16 + lane15;
        boffn[n] = col * 16 + ((g ^ ((col >> 2) & 3)) << 2);
    }

    float bestv[16];
    int   bestc[16];
    #pragma unroll
    for (int i = 0; i < 16; ++i) { bestv[i] = 3.0e38f; bestc[i] = 0; }

    // phase p of kt (global s = kt*16+p): wait vmcnt(1) [chunk s retired; s+1 may fly],
    // barrier, read b64 frags from slot p&3, stage chunk s+2 into slot (p+2)&3
    // (last read 2 phases ago, reads retired at intervening barrier), MFMA burst.
    #define STEP(p_)                                                                   \
    do {                                                                               \
        if ((p_) == 15 && kt == KT_PER - 1) { VMW(0); } else { VMW(1); }               \
        __builtin_amdgcn_s_barrier();                                                  \
        __builtin_amdgcn_sched_barrier(0);                                             \
        f16x4 af[4], bf[4];                                                            \
        const int abase = ((p_) >> 2) * 8192;                                          \
        const int op    = ((p_) & 3) * 2;                                              \
        _Pragma("unroll")                                                              \
        for (int m_ = 0; m_ < 4; ++m_)                                                 \
            af[m_] = *reinterpret_cast<const f16x4*>(                                  \
                lds + abase + rowbase[m_] + (((op + g1) ^ r7[m_]) << 3));              \
        _Pragma("unroll")                                                              \
        for (int n_ = 0; n_ < 4; ++n_)                                                 \
            bf[n_] = *reinterpret_cast<const f16x4*>(                                  \
                ring + ((p_) & 3) * 2048 + boffn[n_]);                                 \
        if ((p_) < 14)                STAGE_C(kt, (p_) + 2);                           \
        else if (kt < KT_PER - 1)     STAGE_C(kt + 1, (p_) - 14);                      \
        __builtin_amdgcn_s_setprio(1);                                                 \
        _Pragma("unroll")                                                              \
        for (int m_ = 0; m_ < 4; ++m_)                                                 \
            _Pragma("unroll")                                                          \
            for (int n_ = 0; n_ < 4; ++n_)                                             \
                acc[m_][n_] = __builtin_amdgcn_mfma_f32_16x16x16f16(                   \
                    af[m_], bf[n_], acc[m_][n_], 0, 0, 0);                             \
        __builtin_amdgcn_s_setprio(0);                                                 \
    } while (0)

    for (int kt = 0; kt < KT_PER; ++kt) {
        f32x4 acc[4][4];
        #pragma unroll
        for (int m = 0; m < 4; ++m)
            #pragma unroll
            for (int n = 0; n < 4; ++n)
                #pragma unroll
                for (int q = 0; q < 4; ++q) acc[m][n][q] = 0.0f;

        STEP(0);  STEP(1);  STEP(2);  STEP(3);
        STEP(4);  STEP(5);  STEP(6);  STEP(7);
        STEP(8);  STEP(9);  STEP(10); STEP(11);
        STEP(12); STEP(13); STEP(14); STEP(15);

        // fold: score = ||e||^2 - 2 z.e ; (kt, n) ascending scan -> first-min kept.
        // enorm loaded here (compiler inserts its own vmcnt drain; 8x per kernel, cheap)
        #pragma unroll
        for (int n = 0; n < 4; ++n) {
            const int c  = kbase + kt * 128 + wn * 64 + n * 16 + lane15;
            const float en = enorm[c];
            #pragma unroll
            for (int m = 0; m < 4; ++m)
                #pragma unroll
                for (int q = 0; q < 4; ++q) {
                    const int sl = m * 4 + q;
                    const float s = fmaf(-2.0f, acc[m][n][q], en);
                    if (s < bestv[sl]) { bestv[sl] = s; bestc[sl] = c; }
                }
        }
    }
    #undef STEP
    #undef STAGE_C

    // tail: per-row top-2 over the 16 lanes sharing each row (lexicographic keys)
    unsigned long long* t2 = reinterpret_cast<unsigned long long*>(lds);  // [wid][64][2]
    #pragma unroll
    for (int sl = 0; sl < 16; ++sl) {
        const int m = sl >> 2, q = sl & 3;
        const unsigned long long k1 = skey(bestv[sl], bestc[sl]);
        unsigned long long m1 = k1;
        #pragma unroll
        for (int msk = 1; msk < 16; msk <<= 1) {
            const unsigned long long o = __shfl_xor(m1, msk);
            m1 = (o < m1) ? o : m1;
        }
        unsigned long long k2 = (k1 == m1) ? ~0ull : k1;
        #pragma unroll
        for (int msk = 1; msk < 16; msk <<= 1) {
            const unsigned long long o = __shfl_xor(k2, msk);
            k2 = (o < k2) ? o : k2;
        }
        if (lane15 == 0) {
            const int row64 = m * 16 + g * 4 + q;
            t2[(wid * 64 + row64) * 2 + 0] = m1;
            t2[(wid * 64 + row64) * 2 + 1] = k2;
        }
    }
    __syncthreads();
    if (tid < 128) {
        const int wm2 = tid >> 6, r64 = tid & 63;
        const unsigned long long a1 = t2[((wm2 * 2 + 0) * 64 + r64) * 2 + 0];
        const unsigned long long a2 = t2[((wm2 * 2 + 0) * 64 + r64) * 2 + 1];
        const unsigned long long b1 = t2[((wm2 * 2 + 1) * 64 + r64) * 2 + 0];
        const unsigned long long b2 = t2[((wm2 * 2 + 1) * 64 + r64) * 2 + 1];
        const unsigned long long r1 = (a1 < b1) ? a1 : b1;
        const unsigned long long hi = (a1 < b1) ? b1 : a1;
        const unsigned long long l2 = (a2 < b2) ? a2 : b2;
        const unsigned long long r2 = (hi < l2) ? hi : l2;
        ulonglong2 res;  res.x = r1;  res.y = r2;
        part2[(size_t)ksp * N_VEC + row0 + tid] = res;
    }
}

// ---------------- kernel 2: merge splits + exact fp64 rescore of global top-4 + loss ----------------
__global__ __launch_bounds__(256) void rescore_kernel(const float* __restrict__ Z,
                                                      const float* __restrict__ E,
                                                      const ulonglong2* __restrict__ part2,
                                                      int* __restrict__ idx_i,
                                                      float* __restrict__ out_idx,
                                                      float* __restrict__ lossp) {
    __shared__ double redl[4];
    const int tid = threadIdx.x, lane = tid & 63, wid = tid >> 6;
    const int r = blockIdx.x * 4 + wid;
    int c0 = 0, c1 = 0, c2 = 0, c3 = 0;
    if (lane == 0) {
        unsigned long long m0 = ~0ull, m1 = ~0ull, m2 = ~0ull, m3 = ~0ull;
        for (int s = 0; s < NSPLIT; ++s) {
            const ulonglong2 p = part2[(size_t)s * N_VEC + r];
            unsigned long long k = p.x;
            if (k < m0) { m3 = m2; m2 = m1; m1 = m0; m0 = k; }
            else if (k < m1) { m3 = m2; m2 = m1; m1 = k; }
            else if (k < m2) { m3 = m2; m2 = k; }
            else if (k < m3) { m3 = k; }
            k = p.y;
            if (k < m0) { m3 = m2; m2 = m1; m1 = m0; m0 = k; }
            else if (k < m1) { m3 = m2; m2 = m1; m1 = k; }
            else if (k < m2) { m3 = m2; m2 = k; }
            else if (k < m3) { m3 = k; }
        }
        c0 = (int)(m0 & 0x1FFFull);  c1 = (int)(m1 & 0x1FFFull);
        c2 = (int)(m2 & 0x1FFFull);  c3 = (int)(m3 & 0x1FFFull);
    }
    c0 = __shfl(c0, 0);  c1 = __shfl(c1, 0);
    c2 = __shfl(c2, 0);  c3 = __shfl(c3, 0);
    const float4 z4 = *reinterpret_cast<const float4*>(Z + (size_t)r * D_DIM + lane * 4);
    double d[4];
    const int cc[4] = {c0, c1, c2, c3};
    #pragma unroll
    for (int j = 0; j < 4; ++j) {
        const float4 e4 = *reinterpret_cast<const float4*>(E + (size_t)cc[j] * D_DIM + lane * 4);
        const double ax = (double)z4.x - (double)e4.x, ay = (double)z4.y - (double)e4.y;
        const double az = (double)z4.z - (double)e4.z, aw = (double)z4.w - (double)e4.w;
        d[j] = ax * ax + ay * ay + az * az + aw * aw;
    }
    #pragma unroll
    for (int off = 1; off < 64; off <<= 1) {
        #pragma unroll
        for (int j = 0; j < 4; ++j) d[j] += __shfl_xor(d[j], off);
    }
    if (lane == 0) {
        double bd = d[0];  int bi = c0;
        #pragma unroll
        for (int j = 1; j < 4; ++j) {
            if (d[j] < bd || (d[j] == bd && cc[j] < bi)) { bd = d[j]; bi = cc[j]; }
        }
        idx_i[r]   = bi;
        out_idx[r] = (float)bi;
        redl[wid]  = bd;            // exact ||z - zq||^2 of the chosen code
    }
    __syncthreads();
    if (tid == 0) lossp[blockIdx.x] = (float)(redl[0] + redl[1] + redl[2] + redl[3]);
}

// ---------------- kernel 3: gather + NCHW transpose ----------------
__global__ __launch_bounds__(256) void gather_kernel(const float* __restrict__ E,
                                                     const int* __restrict__ idx_i,
                                                     float* __restrict__ out) {
    __shared__ float Ls[128 * 65];
    __shared__ int   sIdx[64];

    const int tid = threadIdx.x;
    const int gb  = blockIdx.x;       // 0..255, 64 latent vectors each
    const int n0  = gb * 64;
    const int b   = n0 >> 10;
    const int hwbase = n0 & 1023;

    if (tid < 64) sIdx[tid] = idx_i[n0 + tid];
    __syncthreads();

    for (int h = 0; h < 2; ++h) {
        if (h) __syncthreads();
        const int rowl = tid >> 2;
        const int qs   = tid & 3;
        const float* erow = E + (size_t)sIdx[rowl] * D_DIM + h * 128;
        #pragma unroll
        for (int m = 0; m < 8; ++m) {
            const int c4 = m * 4 + qs;
            const float4 v = *reinterpret_cast<const float4*>(erow + c4 * 4);
            Ls[(c4 * 4 + 0) * 65 + rowl] = v.x;
            Ls[(c4 * 4 + 1) * 65 + rowl] = v.y;
            Ls[(c4 * 4 + 2) * 65 + rowl] = v.z;
            Ls[(c4 * 4 + 3) * 65 + rowl] = v.w;
        }
        __syncthreads();
        const int wl   = tid & 63;
        const int csub = tid >> 6;
        #pragma unroll
        for (int pc = 0; pc < 32; ++pc) {
            const int c_l = pc * 4 + csub;
            const int c   = h * 128 + c_l;
            out[((size_t)(b * 256 + c)) * 1024 + hwbase + wl] = Ls[c_l * 65 + wl];
        }
    }
}

// ---------------- kernel 4: finalize scalars ----------------
__global__ __launch_bounds__(256) void final_kernel(const float* __restrict__ lossp,
                                                    float* __restrict__ out) {
    __shared__ float red[4];
    const int tid = threadIdx.x;
    float s = 0.0f;
    for (int i = tid; i < N_VEC / 4; i += 256) s += lossp[i];
    #pragma unroll
    for (int off = 32; off; off >>= 1) s += __shfl_down(s, off);
    if ((tid & 63) == 0) red[tid >> 6] = s;
    __syncthreads();
    if (tid == 0) {
        const float total = red[0] + red[1] + red[2] + red[3];
        out[DIFF_OFF] = 0.25f * (total / (float)(N_VEC * D_DIM));
        out[PERP_OFF] = 1.0f;
    }
}

// ---------------- launcher ----------------
extern "C" void kernel_launch(void* const* d_in, const int* in_sizes, int n_in,
                              void* d_out, int out_size, void* d_ws, size_t ws_size,
                              hipStream_t stream) {
    const float* Z = (const float*)d_in[0];   // (16,32,32,256) fp32
    const float* E = (const float*)d_in[1];   // (8192,256) fp32
    float* out = (float*)d_out;
    char*  ws  = (char*)d_ws;                 // needs ~14.6 MB

    ulonglong2* part2   = (ulonglong2*)(ws + WS_P2);
    int*        idx_i   = (int*)(ws + WS_IDXI);
    float*      lossbuf = (float*)(ws + WS_LOSS);

    hipLaunchKernelGGL(convert_kernel, dim3((N_VEC + K_CODES) / 4), dim3(256), 0, stream, Z, E, ws);
    hipLaunchKernelGGL(vq_mfma_kernel, dim3(N_VEC / BM, NSPLIT), dim3(256), 0, stream,
                       (const char*)ws, part2);
    hipLaunchKernelGGL(rescore_kernel, dim3(N_VEC / 4), dim3(256), 0, stream,
                       Z, E, part2, idx_i, out + IDX_OFF, lossbuf);
    hipLaunchKernelGGL(gather_kernel, dim3(N_VEC / 64), dim3(256), 0, stream,
                       E, idx_i, out);
    hipLaunchKernelGGL(final_kernel, dim3(1), dim3(256), 0, stream, lossbuf, out);
}

// Round 19
// 128.445 us; speedup vs baseline: 1.1521x; 1.1521x over previous
//
#include <hip/hip_runtime.h>
#include <hip/hip_bf16.h>
#include <hip/hip_fp16.h>

// ---------------- problem constants ----------------
#define N_VEC   16384      // 16*32*32 latent vectors
#define K_CODES 8192
#define D_DIM   256
#define NSPLIT  8          // code-dim splits (grid.y)
#define KT_PER  8          // 1024 cols per split / 128 per kt
#define BM      64         // block rows (A = 32 KB -> ring fits, 2 blocks/CU)

// d_out layout (float32 elements)
#define ZQ_SIZE  (16*256*32*32)          // 4194304
#define DIFF_OFF ZQ_SIZE
#define IDX_OFF  (ZQ_SIZE + 1)
#define PERP_OFF (ZQ_SIZE + 1 + N_VEC)

// ws layout (bytes); ~14.6 MB
#define WS_ENORM 0
#define WS_ZH    65536
#define WS_EH    (WS_ZH + N_VEC * D_DIM * 2)      // +8 MB
#define WS_P2    (WS_EH + K_CODES * D_DIM * 2)    // +4 MB
#define WS_IDXI  (WS_P2 + NSPLIT * N_VEC * 16)    // +2 MB
#define WS_LOSS  (WS_IDXI + N_VEC * 4)            // 4096 floats

typedef _Float16 f16x8 __attribute__((ext_vector_type(8)));
typedef float    f32x4 __attribute__((ext_vector_type(4)));

// monotone (score, idx) 64-bit key: smaller key = smaller score, tie -> smaller idx
__device__ __forceinline__ unsigned long long skey(float s, int c) {
    unsigned u = __float_as_uint(s);
    u ^= (unsigned)((int)u >> 31) | 0x80000000u;
    return ((unsigned long long)u << 13) | (unsigned)c;
}

// Z (A-operand) 16 KB tile: (row 0..127, dloc 0..63 f16), slot = (dloc>>3) ^ (row&7)
__device__ __forceinline__ int swz_off(int row, int dloc) {
    return row * 128 + ((((dloc >> 3) ^ (row & 7))) << 4) + ((dloc & 7) << 1);
}

__device__ __forceinline__ void gload16(const void* g, void* l) {
    __builtin_amdgcn_global_load_lds((const __attribute__((address_space(1))) unsigned int*)g,
                                     (__attribute__((address_space(3))) unsigned int*)l,
                                     16, 0, 0);
}

#define VMW__(n) asm volatile("s_waitcnt vmcnt(" #n ")" ::: "memory")
#define VMW(n) VMW__(n)

// ---------------- kernel 0: fp32 -> fp16 pre-tiled+swizzled, fused codebook norms ----------------
// Z: 16 KB tiles (128 rows x 64 d), slot = (dloc>>3) ^ (row&7)
// E: 8 KB tiles  (128 cols x 32 d), slot = (dloc>>3) ^ ((col>>1)&3)   [r12 layout]
__global__ __launch_bounds__(256) void convert_kernel(const float* __restrict__ Z,
                                                      const float* __restrict__ E,
                                                      char* __restrict__ ws) {
    const int t  = threadIdx.x;
    const int r  = blockIdx.x * 4 + (t >> 6);   // one wave per row
    const int d0 = (t & 63) * 4;
    const float* src;
    char* dh;
    const bool isE = (r >= N_VEC);
    if (!isE) {
        src = Z + (size_t)r * D_DIM;
        const int rowl = r & 127;
        dh = ws + WS_ZH + (size_t)(((r >> 7) * 4) + (d0 >> 6)) * 16384
           + swz_off(rowl, d0 & 63);
    } else {
        const int re = r - N_VEC;
        src = E + (size_t)re * D_DIM;
        const int col  = re & 127;
        const int k32  = d0 >> 5;          // 0..7
        const int dloc = d0 & 31;
        const int slot = (dloc >> 3) ^ ((col >> 1) & 3);
        dh = ws + WS_EH + (size_t)((re >> 7) * 8 + k32) * 8192
           + col * 64 + slot * 16 + (dloc & 7) * 2;
    }
    const float4 v = *reinterpret_cast<const float4*>(src + d0);
    const unsigned h0 = __half_as_ushort(__float2half(v.x));
    const unsigned h1 = __half_as_ushort(__float2half(v.y));
    const unsigned h2 = __half_as_ushort(__float2half(v.z));
    const unsigned h3 = __half_as_ushort(__float2half(v.w));
    uint2 hi;
    hi.x = h0 | (h1 << 16);  hi.y = h2 | (h3 << 16);
    *reinterpret_cast<uint2*>(dh) = hi;

    if (isE) {   // fused ||e||^2 (fp32, exact same reduction as all passing rounds)
        float s = v.x * v.x + v.y * v.y + v.z * v.z + v.w * v.w;
        #pragma unroll
        for (int off = 32; off; off >>= 1) s += __shfl_down(s, off);
        if ((t & 63) == 0) ((float*)(ws + WS_ENORM))[r - N_VEC] = s;
    }
}

// ---------------- kernel 1: fp16 MFMA screen; BM=64, A static in LDS (32 KB),
//   B 4-slot ring of 8 KB chunks (r12 E layout, conflict-free b128 frags) staged
//   2 phases ahead -> per-phase vmcnt(2) (over-wait-safe), one barrier/phase. ----------------
__global__ __launch_bounds__(256, 2) void vq_mfma_kernel(const char* __restrict__ ws_ro,
                                                         ulonglong2* __restrict__ part2) {
    __shared__ short lds[34816];   // A:[0,16384) ring:[16384,32768) 4x4096 enl:[32768,34816)

    const int tid  = threadIdx.x;
    const int lane = tid & 63, wid = tid >> 6;
    const int lane15 = lane & 15, g = lane >> 4;
    const int l7  = lane15 & 7;
    const int c13 = (lane15 >> 1) & 3;
    const int wm = wid >> 1, wn = wid & 1;
    const int bx = blockIdx.x, ksp = blockIdx.y;
    const int row0 = bx * BM;
    const int kbase = ksp * (K_CODES / NSPLIT);
    const int rg = bx >> 1, hh = bx & 1;   // 128-row tile group, 64-row half

    const char* zh = ws_ro + WS_ZH;
    const char* eh = ws_ro + WS_EH;
    float* enl = (float*)(lds + 32768);

    // stage one 8 KB chunk (kt_, j_): cols [kbase+kt_*128,+128) x d [32*j_,+32)
    // ring slot = (kt_*8+j_)%4 = j_&3 (kt*8 ≡ 0 mod 4); 2 gload16/thread
    #define STAGE_C(kt_, j_)                                                           \
    do {                                                                               \
        const char* sB = eh + (size_t)(((ksp * 8 + (kt_)) * 8) + (j_)) * 8192          \
                            + wid * 2048 + lane * 16;                                  \
        short* dB = lds + 16384 + ((j_) & 3) * 4096 + wid * 1024 + lane * 8;           \
        gload16(sB, dB);                                                               \
        gload16(sB + 1024, dB + 512);                                                  \
    } while (0)

    // ---- prologue: A (32 KB linear: 4 d-tiles x 8 KB half-tile slices) ----
    {
        const char* srcA = zh + (size_t)(rg * 4) * 16384 + hh * 8192;
        #pragma unroll
        for (int i = 0; i < 8; ++i)
            gload16(srcA + (i >> 1) * 16384 + (i & 1) * 4096 + tid * 16,
                    lds + i * 2048 + tid * 8);
    }
    // enorm slice (4 KB) -> LDS (ds-reads later: no vmcnt pollution)
    gload16((const char*)(ws_ro + WS_ENORM) + ksp * 4096 + tid * 16,
            (char*)enl + tid * 16);
    __builtin_amdgcn_sched_barrier(0);
    STAGE_C(0, 0);
    STAGE_C(0, 1);
    VMW(2);                          // A + enorm + chunk0 retired; chunk1 (2 ops) may fly
    __builtin_amdgcn_s_barrier();
    __builtin_amdgcn_sched_barrier(0);

    // loop-invariant fragment terms (shorts) — byte math identical to r12
    int rowterm[2];
    #pragma unroll
    for (int m = 0; m < 2; ++m) rowterm[m] = (wm * 32 + m * 16 + lane15) * 64;
    int colterm[4];
    #pragma unroll
    for (int n = 0; n < 4; ++n) colterm[n] = (wn * 64 + n * 16 + lane15) * 32;
    const int sa0 = (g ^ l7) * 8;        // A slot term, j even; j odd -> ^32
    const int sb  = (g ^ c13) * 8;       // B slot term

    float bestv[8];
    int   bestc[8];
    #pragma unroll
    for (int i = 0; i < 8; ++i) { bestv[i] = 3.0e38f; bestc[i] = 0; }

    // phase j of kt (global s = kt*8+j): wait vmcnt(2) [chunk s retired; s+1's 2 loads
    // may fly — oldest-first retirement makes this over-wait-safe], one barrier, read
    // b128 frags from slot j&3, stage chunk s+2 into slot (j+2)&3 (its last reads were
    // phase s-2, retired before barrier(s-1) per the r12-proven argument), MFMA burst.
    #define STEP(j_)                                                                   \
    do {                                                                               \
        if ((j_) == 7 && kt == KT_PER - 1) { VMW(0); } else { VMW(2); }                \
        __builtin_amdgcn_s_barrier();                                                  \
        __builtin_amdgcn_sched_barrier(0);                                             \
        f16x8 af[2], bf[4];                                                            \
        const int abase = ((j_) >> 1) * 4096 + (sa0 ^ (((j_) & 1) << 5));              \
        const int bbase = 16384 + ((j_) & 3) * 4096 + sb;                              \
        _Pragma("unroll")                                                              \
        for (int m_ = 0; m_ < 2; ++m_)                                                 \
            af[m_] = *reinterpret_cast<const f16x8*>(lds + abase + rowterm[m_]);       \
        _Pragma("unroll")                                                              \
        for (int n_ = 0; n_ < 4; ++n_)                                                 \
            bf[n_] = *reinterpret_cast<const f16x8*>(lds + bbase + colterm[n_]);       \
        if ((j_) < 6)                 STAGE_C(kt, (j_) + 2);                           \
        else if (kt < KT_PER - 1)     STAGE_C(kt + 1, (j_) - 6);                       \
        __builtin_amdgcn_s_setprio(1);                                                 \
        _Pragma("unroll")                                                              \
        for (int m_ = 0; m_ < 2; ++m_)                                                 \
            _Pragma("unroll")                                                          \
            for (int n_ = 0; n_ < 4; ++n_)                                             \
                acc[m_][n_] = __builtin_amdgcn_mfma_f32_16x16x32_f16(                  \
                    af[m_], bf[n_], acc[m_][n_], 0, 0, 0);                             \
        __builtin_amdgcn_s_setprio(0);                                                 \
    } while (0)

    for (int kt = 0; kt < KT_PER; ++kt) {
        f32x4 acc[2][4];
        #pragma unroll
        for (int m = 0; m < 2; ++m)
            #pragma unroll
            for (int n = 0; n < 4; ++n)
                #pragma unroll
                for (int q = 0; q < 4; ++q) acc[m][n][q] = 0.0f;

        STEP(0); STEP(1); STEP(2); STEP(3);
        STEP(4); STEP(5); STEP(6); STEP(7);

        // fold: score = ||e||^2 - 2 z.e ; (kt, n) ascending scan -> first-min kept
        #pragma unroll
        for (int n = 0; n < 4; ++n) {
            const int cl = kt * 128 + wn * 64 + n * 16 + lane15;
            const int c  = kbase + cl;
            const float en = enl[cl];
            #pragma unroll
            for (int m = 0; m < 2; ++m)
                #pragma unroll
                for (int q = 0; q < 4; ++q) {
                    const int sl = m * 4 + q;
                    const float s = fmaf(-2.0f, acc[m][n][q], en);
                    if (s < bestv[sl]) { bestv[sl] = s; bestc[sl] = c; }
                }
        }
    }
    #undef STEP
    #undef STAGE_C

    // tail: per-wave top-2 per row (16-lane butterfly), then merge the 2 wn-waves
    __syncthreads();
    unsigned long long* t2 = reinterpret_cast<unsigned long long*>(lds);  // [wid][32][2]
    #pragma unroll
    for (int sl = 0; sl < 8; ++sl) {
        const int m = sl >> 2, q = sl & 3;
        const unsigned long long k1 = skey(bestv[sl], bestc[sl]);
        unsigned long long m1 = k1;
        #pragma unroll
        for (int msk = 1; msk < 16; msk <<= 1) {
            const unsigned long long o = __shfl_xor(m1, msk);
            m1 = (o < m1) ? o : m1;
        }
        unsigned long long k2 = (k1 == m1) ? ~0ull : k1;
        #pragma unroll
        for (int msk = 1; msk < 16; msk <<= 1) {
            const unsigned long long o = __shfl_xor(k2, msk);
            k2 = (o < k2) ? o : k2;
        }
        if (lane15 == 0) {
            const int row32 = m * 16 + g * 4 + q;   // C/D: row=(lane>>4)*4+q
            t2[(wid * 32 + row32) * 2 + 0] = m1;
            t2[(wid * 32 + row32) * 2 + 1] = k2;
        }
    }
    __syncthreads();
    if (tid < 64) {
        const int wmg = tid >> 5, lr = tid & 31;
        unsigned long long m0 = ~0ull, m1 = ~0ull;
        #pragma unroll
        for (int w = 0; w < 2; ++w) {
            #pragma unroll
            for (int k = 0; k < 2; ++k) {
                const unsigned long long key = t2[(((wmg * 2 + w) * 32) + lr) * 2 + k];
                if (key < m0) { m1 = m0; m0 = key; }
                else if (key < m1) { m1 = key; }
            }
        }
        ulonglong2 res;  res.x = m0;  res.y = m1;
        part2[(size_t)ksp * N_VEC + row0 + tid] = res;
    }
}

// ---------------- kernel 2: merge splits + exact fp64 rescore of global top-4 + loss ----------------
__global__ __launch_bounds__(256) void rescore_kernel(const float* __restrict__ Z,
                                                      const float* __restrict__ E,
                                                      const ulonglong2* __restrict__ part2,
                                                      int* __restrict__ idx_i,
                                                      float* __restrict__ out_idx,
                                                      float* __restrict__ lossp) {
    __shared__ double redl[4];
    const int tid = threadIdx.x, lane = tid & 63, wid = tid >> 6;
    const int r = blockIdx.x * 4 + wid;
    int c0 = 0, c1 = 0, c2 = 0, c3 = 0;
    if (lane == 0) {
        unsigned long long m0 = ~0ull, m1 = ~0ull, m2 = ~0ull, m3 = ~0ull;
        for (int s = 0; s < NSPLIT; ++s) {
            const ulonglong2 p = part2[(size_t)s * N_VEC + r];
            unsigned long long k = p.x;
            if (k < m0) { m3 = m2; m2 = m1; m1 = m0; m0 = k; }
            else if (k < m1) { m3 = m2; m2 = m1; m1 = k; }
            else if (k < m2) { m3 = m2; m2 = k; }
            else if (k < m3) { m3 = k; }
            k = p.y;
            if (k < m0) { m3 = m2; m2 = m1; m1 = m0; m0 = k; }
            else if (k < m1) { m3 = m2; m2 = m1; m1 = k; }
            else if (k < m2) { m3 = m2; m2 = k; }
            else if (k < m3) { m3 = k; }
        }
        c0 = (int)(m0 & 0x1FFFull);  c1 = (int)(m1 & 0x1FFFull);
        c2 = (int)(m2 & 0x1FFFull);  c3 = (int)(m3 & 0x1FFFull);
    }
    c0 = __shfl(c0, 0);  c1 = __shfl(c1, 0);
    c2 = __shfl(c2, 0);  c3 = __shfl(c3, 0);
    const float4 z4 = *reinterpret_cast<const float4*>(Z + (size_t)r * D_DIM + lane * 4);
    double d[4];
    const int cc[4] = {c0, c1, c2, c3};
    #pragma unroll
    for (int j = 0; j < 4; ++j) {
        const float4 e4 = *reinterpret_cast<const float4*>(E + (size_t)cc[j] * D_DIM + lane * 4);
        const double ax = (double)z4.x - (double)e4.x, ay = (double)z4.y - (double)e4.y;
        const double az = (double)z4.z - (double)e4.z, aw = (double)z4.w - (double)e4.w;
        d[j] = ax * ax + ay * ay + az * az + aw * aw;
    }
    #pragma unroll
    for (int off = 1; off < 64; off <<= 1) {
        #pragma unroll
        for (int j = 0; j < 4; ++j) d[j] += __shfl_xor(d[j], off);
    }
    if (lane == 0) {
        double bd = d[0];  int bi = c0;
        #pragma unroll
        for (int j = 1; j < 4; ++j) {
            if (d[j] < bd || (d[j] == bd && cc[j] < bi)) { bd = d[j]; bi = cc[j]; }
        }
        idx_i[r]   = bi;
        out_idx[r] = (float)bi;
        redl[wid]  = bd;            // exact ||z - zq||^2 of the chosen code
    }
    __syncthreads();
    if (tid == 0) lossp[blockIdx.x] = (float)(redl[0] + redl[1] + redl[2] + redl[3]);
}

// ---------------- kernel 3: gather + NCHW transpose ----------------
__global__ __launch_bounds__(256) void gather_kernel(const float* __restrict__ E,
                                                     const int* __restrict__ idx_i,
                                                     float* __restrict__ out) {
    __shared__ float Ls[128 * 65];
    __shared__ int   sIdx[64];

    const int tid = threadIdx.x;
    const int gb  = blockIdx.x;       // 0..255, 64 latent vectors each
    const int n0  = gb * 64;
    const int b   = n0 >> 10;
    const int hwbase = n0 & 1023;

    if (tid < 64) sIdx[tid] = idx_i[n0 + tid];
    __syncthreads();

    for (int h = 0; h < 2; ++h) {
        if (h) __syncthreads();
        const int rowl = tid >> 2;
        const int qs   = tid & 3;
        const float* erow = E + (size_t)sIdx[rowl] * D_DIM + h * 128;
        #pragma unroll
        for (int m = 0; m < 8; ++m) {
            const int c4 = m * 4 + qs;
            const float4 v = *reinterpret_cast<const float4*>(erow + c4 * 4);
            Ls[(c4 * 4 + 0) * 65 + rowl] = v.x;
            Ls[(c4 * 4 + 1) * 65 + rowl] = v.y;
            Ls[(c4 * 4 + 2) * 65 + rowl] = v.z;
            Ls[(c4 * 4 + 3) * 65 + rowl] = v.w;
        }
        __syncthreads();
        const int wl   = tid & 63;
        const int csub = tid >> 6;
        #pragma unroll
        for (int pc = 0; pc < 32; ++pc) {
            const int c_l = pc * 4 + csub;
            const int c   = h * 128 + c_l;
            out[((size_t)(b * 256 + c)) * 1024 + hwbase + wl] = Ls[c_l * 65 + wl];
        }
    }
}

// ---------------- kernel 4: finalize scalars ----------------
__global__ __launch_bounds__(256) void final_kernel(const float* __restrict__ lossp,
                                                    float* __restrict__ out) {
    __shared__ float red[4];
    const int tid = threadIdx.x;
    float s = 0.0f;
    for (int i = tid; i < N_VEC / 4; i += 256) s += lossp[i];
    #pragma unroll
    for (int off = 32; off; off >>= 1) s += __shfl_down(s, off);
    if ((tid & 63) == 0) red[tid >> 6] = s;
    __syncthreads();
    if (tid == 0) {
        const float total = red[0] + red[1] + red[2] + red[3];
        out[DIFF_OFF] = 0.25f * (total / (float)(N_VEC * D_DIM));
        out[PERP_OFF] = 1.0f;
    }
}

// ---------------- launcher ----------------
extern "C" void kernel_launch(void* const* d_in, const int* in_sizes, int n_in,
                              void* d_out, int out_size, void* d_ws, size_t ws_size,
                              hipStream_t stream) {
    const float* Z = (const float*)d_in[0];   // (16,32,32,256) fp32
    const float* E = (const float*)d_in[1];   // (8192,256) fp32
    float* out = (float*)d_out;
    char*  ws  = (char*)d_ws;                 // needs ~14.6 MB

    ulonglong2* part2   = (ulonglong2*)(ws + WS_P2);
    int*        idx_i   = (int*)(ws + WS_IDXI);
    float*      lossbuf = (float*)(ws + WS_LOSS);

    hipLaunchKernelGGL(convert_kernel, dim3((N_VEC + K_CODES) / 4), dim3(256), 0, stream, Z, E, ws);
    hipLaunchKernelGGL(vq_mfma_kernel, dim3(N_VEC / BM, NSPLIT), dim3(256), 0, stream,
                       (const char*)ws, part2);
    hipLaunchKernelGGL(rescore_kernel, dim3(N_VEC / 4), dim3(256), 0, stream,
                       Z, E, part2, idx_i, out + IDX_OFF, lossbuf);
    hipLaunchKernelGGL(gather_kernel, dim3(N_VEC / 64), dim3(256), 0, stream,
                       E, idx_i, out);
    hipLaunchKernelGGL(final_kernel, dim3(1), dim3(256), 0, stream, lossbuf, out);
}

// Round 20
// 118.791 us; speedup vs baseline: 1.2457x; 1.0813x over previous
//
#include <hip/hip_runtime.h>
#include <hip/hip_bf16.h>
#include <hip/hip_fp16.h>

// ---------------- problem constants ----------------
#define N_VEC   16384      // 16*32*32 latent vectors
#define K_CODES 8192
#define D_DIM   256
#define NSPLIT  8          // code-dim splits (grid.y)
#define KT_PER  8          // 1024 cols per split / 128 per kt
#define BM      128

// d_out layout (float32 elements)
#define ZQ_SIZE  (16*256*32*32)          // 4194304
#define DIFF_OFF ZQ_SIZE
#define IDX_OFF  (ZQ_SIZE + 1)
#define PERP_OFF (ZQ_SIZE + 1 + N_VEC)

// ws layout (bytes); ~14.6 MB
#define WS_ENORM 0
#define WS_ZH    65536
#define WS_EH    (WS_ZH + N_VEC * D_DIM * 2)      // +8 MB
#define WS_P2    (WS_EH + K_CODES * D_DIM * 2)    // +4 MB
#define WS_IDXI  (WS_P2 + NSPLIT * N_VEC * 16)    // +2 MB
#define WS_LOSS  (WS_IDXI + N_VEC * 4)            // 4096 floats

typedef _Float16 f16x8 __attribute__((ext_vector_type(8)));
typedef float    f32x4 __attribute__((ext_vector_type(4)));

// monotone (score, idx) 64-bit key: smaller key = smaller score, tie -> smaller idx
__device__ __forceinline__ unsigned long long skey(float s, int c) {
    unsigned u = __float_as_uint(s);
    u ^= (unsigned)((int)u >> 31) | 0x80000000u;
    return ((unsigned long long)u << 13) | (unsigned)c;
}

// Z (A-operand) 16 KB tile: (row 0..127, dloc 0..63 f16), slot = (dloc>>3) ^ (row&7)
__device__ __forceinline__ int swz_off(int row, int dloc) {
    return row * 128 + ((((dloc >> 3) ^ (row & 7))) << 4) + ((dloc & 7) << 1);
}

__device__ __forceinline__ void gload16(const void* g, void* l) {
    __builtin_amdgcn_global_load_lds((const __attribute__((address_space(1))) unsigned int*)g,
                                     (__attribute__((address_space(3))) unsigned int*)l,
                                     16, 0, 0);
}

// ---------------- kernel 0: fp32 -> fp16 pre-tiled+swizzled, fused codebook norms ----------------
// Z: 16 KB tiles (128 rows x 64 d), slot = (dloc>>3) ^ (row&7)
// E: 8 KB tiles  (128 cols x 32 d), slot = (dloc>>3) ^ ((col>>1)&3)   [BK=32 stage chunks]
__global__ __launch_bounds__(256) void convert_kernel(const float* __restrict__ Z,
                                                      const float* __restrict__ E,
                                                      char* __restrict__ ws) {
    const int t  = threadIdx.x;
    const int r  = blockIdx.x * 4 + (t >> 6);   // one wave per row
    const int d0 = (t & 63) * 4;
    const float* src;
    char* dh;
    const bool isE = (r >= N_VEC);
    if (!isE) {
        src = Z + (size_t)r * D_DIM;
        const int rowl = r & 127;
        dh = ws + WS_ZH + (size_t)(((r >> 7) * 4) + (d0 >> 6)) * 16384
           + swz_off(rowl, d0 & 63);
    } else {
        const int re = r - N_VEC;
        src = E + (size_t)re * D_DIM;
        const int col  = re & 127;
        const int k32  = d0 >> 5;          // 0..7
        const int dloc = d0 & 31;
        const int slot = (dloc >> 3) ^ ((col >> 1) & 3);
        dh = ws + WS_EH + (size_t)((re >> 7) * 8 + k32) * 8192
           + col * 64 + slot * 16 + (dloc & 7) * 2;
    }
    const float4 v = *reinterpret_cast<const float4*>(src + d0);
    const unsigned h0 = __half_as_ushort(__float2half(v.x));
    const unsigned h1 = __half_as_ushort(__float2half(v.y));
    const unsigned h2 = __half_as_ushort(__float2half(v.z));
    const unsigned h3 = __half_as_ushort(__float2half(v.w));
    uint2 hi;
    hi.x = h0 | (h1 << 16);  hi.y = h2 | (h3 << 16);
    *reinterpret_cast<uint2*>(dh) = hi;

    if (isE) {   // fused ||e||^2 (fp32, exact same reduction as all passing rounds)
        float s = v.x * v.x + v.y * v.y + v.z * v.z + v.w * v.w;
        #pragma unroll
        for (int off = 32; off; off >>= 1) s += __shfl_down(s, off);
        if ((t & 63) == 0) ((float*)(ws + WS_ENORM))[r - N_VEC] = s;
    }
}

// ---------------- kernel 1: fp16 MFMA screen (r12-exact, best measured 84.5 us):
//   A static in LDS, B dbuf 8 KB chunks; single-barrier phase: vmcnt(0) ->
//   s_barrier -> { ds_read | STAGE next | MFMA } compiler-interleaved. ----------------
__global__ __launch_bounds__(256, 2) void vq_mfma_kernel(const char* __restrict__ ws_ro,
                                                         ulonglong2* __restrict__ part2) {
    __shared__ short lds[40960];   // A: [0,32768) shorts (64 KB); B dbuf: [32768,40960) (16 KB)

    const int tid  = threadIdx.x;
    const int lane = tid & 63, wid = tid >> 6;
    const int lane15 = lane & 15, g = lane >> 4;
    const int l7  = lane15 & 7;
    const int c13 = (lane15 >> 1) & 3;
    const int wm = wid >> 1, wn = wid & 1;
    const int bx = blockIdx.x, ksp = blockIdx.y;
    const int row0 = bx * BM;
    const int kbase = ksp * (K_CODES / NSPLIT);

    const char* zh = ws_ro + WS_ZH;
    const char* eh = ws_ro + WS_EH;
    const float* enorm = (const float*)(ws_ro + WS_ENORM);

    #define STAGE_B(kt_, j_)                                                           \
    do {                                                                               \
        const char* sB = eh + (size_t)(((ksp * 8 + (kt_)) * 8) + (j_)) * 8192          \
                            + wid * 2048 + lane * 16;                                  \
        short* dB = lds + 32768 + ((j_) & 1) * 4096 + wid * 1024 + lane * 8;           \
        gload16(sB, dB);                                                               \
        gload16(sB + 1024, dB + 512);                                                  \
    } while (0)

    {
        const char* srcA = zh + (size_t)bx * 65536 + wid * 16384 + lane * 16;
        short* dA = lds + wid * 8192 + lane * 8;
        #pragma unroll
        for (int i = 0; i < 16; ++i) gload16(srcA + i * 1024, dA + i * 512);
    }
    STAGE_B(0, 0);
    float en_c[4], en_n[4];
    #pragma unroll
    for (int n = 0; n < 4; ++n) en_c[n] = enorm[kbase + wn * 64 + n * 16 + lane15];
    asm volatile("s_waitcnt vmcnt(0)" ::: "memory");
    __builtin_amdgcn_s_barrier();
    __builtin_amdgcn_sched_barrier(0);

    int rowterm[4];
    #pragma unroll
    for (int m = 0; m < 4; ++m) rowterm[m] = (wm * 64 + m * 16 + lane15) * 64;
    int colterm[4];
    #pragma unroll
    for (int n = 0; n < 4; ++n) colterm[n] = (wn * 64 + n * 16 + lane15) * 32;
    const int sa0 = (g ^ l7) * 8;
    const int sb  = (g ^ c13) * 8;

    float bestv[16];
    int   bestc[16];
    #pragma unroll
    for (int i = 0; i < 16; ++i) { bestv[i] = 3.0e38f; bestc[i] = 0; }

    #define STEP(j_)                                                                   \
    do {                                                                               \
        asm volatile("s_waitcnt vmcnt(0)" ::: "memory");                               \
        __builtin_amdgcn_s_barrier();                                                  \
        __builtin_amdgcn_sched_barrier(0);                                             \
        f16x8 af[4], bf[4];                                                            \
        const int abase = ((j_) >> 1) * 8192 + (sa0 ^ (((j_) & 1) << 5));              \
        const int bbase = 32768 + ((j_) & 1) * 4096 + sb;                              \
        _Pragma("unroll")                                                              \
        for (int m = 0; m < 4; ++m)                                                    \
            af[m] = *reinterpret_cast<const f16x8*>(lds + abase + rowterm[m]);         \
        _Pragma("unroll")                                                              \
        for (int n = 0; n < 4; ++n)                                                    \
            bf[n] = *reinterpret_cast<const f16x8*>(lds + bbase + colterm[n]);         \
        if ((j_) < 7) {                                                                \
            STAGE_B(kt, (j_) + 1);                                                     \
        } else if (kt < KT_PER - 1) {                                                  \
            STAGE_B(kt + 1, 0);                                                        \
            _Pragma("unroll")                                                          \
            for (int n = 0; n < 4; ++n)                                                \
                en_n[n] = enorm[kbase + (kt + 1) * 128 + wn * 64 + n * 16 + lane15];   \
        }                                                                              \
        __builtin_amdgcn_s_setprio(1);                                                 \
        _Pragma("unroll")                                                              \
        for (int m = 0; m < 4; ++m)                                                    \
            _Pragma("unroll")                                                          \
            for (int n = 0; n < 4; ++n)                                                \
                acc[m][n] = __builtin_amdgcn_mfma_f32_16x16x32_f16(                    \
                    af[m], bf[n], acc[m][n], 0, 0, 0);                                 \
        __builtin_amdgcn_s_setprio(0);                                                 \
    } while (0)

    for (int kt = 0; kt < KT_PER; ++kt) {
        f32x4 acc[4][4];
        #pragma unroll
        for (int m = 0; m < 4; ++m)
            #pragma unroll
            for (int n = 0; n < 4; ++n)
                #pragma unroll
                for (int q = 0; q < 4; ++q) acc[m][n][q] = 0.0f;

        STEP(0); STEP(1); STEP(2); STEP(3);
        STEP(4); STEP(5); STEP(6); STEP(7);

        #pragma unroll
        for (int m = 0; m < 4; ++m)
            #pragma unroll
            for (int n = 0; n < 4; ++n) {
                const int c = kbase + kt * 128 + wn * 64 + n * 16 + lane15;
                #pragma unroll
                for (int q = 0; q < 4; ++q) {
                    const int sl = m * 4 + q;
                    const float s = fmaf(-2.0f, acc[m][n][q], en_c[n]);
                    if (s < bestv[sl]) { bestv[sl] = s; bestc[sl] = c; }
                }
            }
        #pragma unroll
        for (int n = 0; n < 4; ++n) en_c[n] = en_n[n];
    }
    #undef STEP
    #undef STAGE_B

    // tail: per-row top-2 over the 16 lanes sharing each row (lexicographic keys)
    unsigned long long* t2 = reinterpret_cast<unsigned long long*>(lds);  // [wid][64][2]
    #pragma unroll
    for (int sl = 0; sl < 16; ++sl) {
        const int m = sl >> 2, q = sl & 3;
        const unsigned long long k1 = skey(bestv[sl], bestc[sl]);
        unsigned long long m1 = k1;
        #pragma unroll
        for (int msk = 1; msk < 16; msk <<= 1) {
            const unsigned long long o = __shfl_xor(m1, msk);
            m1 = (o < m1) ? o : m1;
        }
        unsigned long long k2 = (k1 == m1) ? ~0ull : k1;
        #pragma unroll
        for (int msk = 1; msk < 16; msk <<= 1) {
            const unsigned long long o = __shfl_xor(k2, msk);
            k2 = (o < k2) ? o : k2;
        }
        if (lane15 == 0) {
            const int row64 = m * 16 + g * 4 + q;
            t2[(wid * 64 + row64) * 2 + 0] = m1;
            t2[(wid * 64 + row64) * 2 + 1] = k2;
        }
    }
    __syncthreads();
    if (tid < 128) {
        const int wm2 = tid >> 6, r64 = tid & 63;
        const unsigned long long a1 = t2[((wm2 * 2 + 0) * 64 + r64) * 2 + 0];
        const unsigned long long a2 = t2[((wm2 * 2 + 0) * 64 + r64) * 2 + 1];
        const unsigned long long b1 = t2[((wm2 * 2 + 1) * 64 + r64) * 2 + 0];
        const unsigned long long b2 = t2[((wm2 * 2 + 1) * 64 + r64) * 2 + 1];
        const unsigned long long r1 = (a1 < b1) ? a1 : b1;
        const unsigned long long hi = (a1 < b1) ? b1 : a1;
        const unsigned long long l2 = (a2 < b2) ? a2 : b2;
        const unsigned long long r2 = (hi < l2) ? hi : l2;
        ulonglong2 res;  res.x = r1;  res.y = r2;
        part2[(size_t)ksp * N_VEC + row0 + tid] = res;
    }
}

// ---------------- kernel 2: fused merge + fp64 rescore + z_q scatter + loss ----------------
// 4096 blocks x 256 threads; block owns rows n0..n0+3 (1 row/wave) — same parallelism
// as the proven standalone rescore, plus a coalesced z_q write phase.
__global__ __launch_bounds__(256) void rescore_kernel(const float* __restrict__ Z,
                                                      const float* __restrict__ E,
                                                      const ulonglong2* __restrict__ part2,
                                                      float* __restrict__ out,
                                                      float* __restrict__ out_idx,
                                                      float* __restrict__ lossp) {
    __shared__ double redl[4];
    __shared__ int    sIdx[4];
    const int tid = threadIdx.x, lane = tid & 63, wid = tid >> 6;
    const int n0 = blockIdx.x * 4;
    const int r  = n0 + wid;
    int c0 = 0, c1 = 0, c2 = 0, c3 = 0;
    if (lane == 0) {
        unsigned long long m0 = ~0ull, m1 = ~0ull, m2 = ~0ull, m3 = ~0ull;
        for (int s = 0; s < NSPLIT; ++s) {
            const ulonglong2 p = part2[(size_t)s * N_VEC + r];
            unsigned long long k = p.x;
            if (k < m0) { m3 = m2; m2 = m1; m1 = m0; m0 = k; }
            else if (k < m1) { m3 = m2; m2 = m1; m1 = k; }
            else if (k < m2) { m3 = m2; m2 = k; }
            else if (k < m3) { m3 = k; }
            k = p.y;
            if (k < m0) { m3 = m2; m2 = m1; m1 = m0; m0 = k; }
            else if (k < m1) { m3 = m2; m2 = m1; m1 = k; }
            else if (k < m2) { m3 = m2; m2 = k; }
            else if (k < m3) { m3 = k; }
        }
        c0 = (int)(m0 & 0x1FFFull);  c1 = (int)(m1 & 0x1FFFull);
        c2 = (int)(m2 & 0x1FFFull);  c3 = (int)(m3 & 0x1FFFull);
    }
    c0 = __shfl(c0, 0);  c1 = __shfl(c1, 0);
    c2 = __shfl(c2, 0);  c3 = __shfl(c3, 0);
    const float4 z4 = *reinterpret_cast<const float4*>(Z + (size_t)r * D_DIM + lane * 4);
    double d[4];
    const int cc[4] = {c0, c1, c2, c3};
    #pragma unroll
    for (int j = 0; j < 4; ++j) {
        const float4 e4 = *reinterpret_cast<const float4*>(E + (size_t)cc[j] * D_DIM + lane * 4);
        const double ax = (double)z4.x - (double)e4.x, ay = (double)z4.y - (double)e4.y;
        const double az = (double)z4.z - (double)e4.z, aw = (double)z4.w - (double)e4.w;
        d[j] = ax * ax + ay * ay + az * az + aw * aw;
    }
    #pragma unroll
    for (int off = 1; off < 64; off <<= 1) {
        #pragma unroll
        for (int j = 0; j < 4; ++j) d[j] += __shfl_xor(d[j], off);
    }
    if (lane == 0) {
        double bd = d[0];  int bi = c0;
        #pragma unroll
        for (int j = 1; j < 4; ++j) {
            if (d[j] < bd || (d[j] == bd && cc[j] < bi)) { bd = d[j]; bi = cc[j]; }
        }
        out_idx[r] = (float)bi;
        sIdx[wid]  = bi;
        redl[wid]  = bd;            // exact ||z - zq||^2 of the chosen code
    }
    __syncthreads();
    if (tid == 0) lossp[blockIdx.x] = (float)(redl[0] + redl[1] + redl[2] + redl[3]);

    // z_q scatter: thread tid owns channel c; rows n0..n0+3 are contiguous hw in one b
    // (n0 multiple of 4, b-groups of 1024). float4 write 16B-aligned (hw0 % 4 == 0).
    {
        const int c   = tid;
        const int b   = n0 >> 10;
        const int hw0 = n0 & 1023;
        float4 v;
        v.x = E[(size_t)sIdx[0] * D_DIM + c];
        v.y = E[(size_t)sIdx[1] * D_DIM + c];
        v.z = E[(size_t)sIdx[2] * D_DIM + c];
        v.w = E[(size_t)sIdx[3] * D_DIM + c];
        *reinterpret_cast<float4*>(out + ((size_t)(b * 256 + c)) * 1024 + hw0) = v;
    }
}

// ---------------- kernel 3: finalize scalars ----------------
__global__ __launch_bounds__(256) void final_kernel(const float* __restrict__ lossp,
                                                    float* __restrict__ out) {
    __shared__ float red[4];
    const int tid = threadIdx.x;
    float s = 0.0f;
    for (int i = tid; i < N_VEC / 4; i += 256) s += lossp[i];
    #pragma unroll
    for (int off = 32; off; off >>= 1) s += __shfl_down(s, off);
    if ((tid & 63) == 0) red[tid >> 6] = s;
    __syncthreads();
    if (tid == 0) {
        const float total = red[0] + red[1] + red[2] + red[3];
        out[DIFF_OFF] = 0.25f * (total / (float)(N_VEC * D_DIM));
        out[PERP_OFF] = 1.0f;
    }
}

// ---------------- launcher ----------------
extern "C" void kernel_launch(void* const* d_in, const int* in_sizes, int n_in,
                              void* d_out, int out_size, void* d_ws, size_t ws_size,
                              hipStream_t stream) {
    const float* Z = (const float*)d_in[0];   // (16,32,32,256) fp32
    const float* E = (const float*)d_in[1];   // (8192,256) fp32
    float* out = (float*)d_out;
    char*  ws  = (char*)d_ws;                 // needs ~14.6 MB

    ulonglong2* part2   = (ulonglong2*)(ws + WS_P2);
    float*      lossbuf = (float*)(ws + WS_LOSS);

    hipLaunchKernelGGL(convert_kernel, dim3((N_VEC + K_CODES) / 4), dim3(256), 0, stream, Z, E, ws);
    hipLaunchKernelGGL(vq_mfma_kernel, dim3(N_VEC / BM, NSPLIT), dim3(256), 0, stream,
                       (const char*)ws, part2);
    hipLaunchKernelGGL(rescore_kernel, dim3(N_VEC / 4), dim3(256), 0, stream,
                       Z, E, part2, out, out + IDX_OFF, lossbuf);
    hipLaunchKernelGGL(final_kernel, dim3(1), dim3(256), 0, stream, lossbuf, out);
}

// Round 21
// 117.495 us; speedup vs baseline: 1.2594x; 1.0110x over previous
//
#include <hip/hip_runtime.h>
#include <hip/hip_bf16.h>
#include <hip/hip_fp16.h>

// ---------------- problem constants ----------------
#define N_VEC   16384      // 16*32*32 latent vectors
#define K_CODES 8192
#define D_DIM   256
#define NSPLIT  8          // code-dim splits (grid.y)
#define KT_PER  8          // 1024 cols per split / 128 per kt
#define BM      128

// d_out layout (float32 elements)
#define ZQ_SIZE  (16*256*32*32)          // 4194304
#define DIFF_OFF ZQ_SIZE
#define IDX_OFF  (ZQ_SIZE + 1)
#define PERP_OFF (ZQ_SIZE + 1 + N_VEC)

// ws layout (bytes); ~14.6 MB
#define WS_ENORM 0
#define WS_ZH    65536
#define WS_EH    (WS_ZH + N_VEC * D_DIM * 2)      // +8 MB
#define WS_P2    (WS_EH + K_CODES * D_DIM * 2)    // +4 MB
#define WS_IDXI  (WS_P2 + NSPLIT * N_VEC * 16)    // +2 MB
#define WS_LOSS  (WS_IDXI + N_VEC * 4)            // 4096 floats

typedef _Float16 f16x8 __attribute__((ext_vector_type(8)));
typedef float    f32x4 __attribute__((ext_vector_type(4)));

// monotone (score, idx) 64-bit key: smaller key = smaller score, tie -> smaller idx
__device__ __forceinline__ unsigned long long skey(float s, int c) {
    unsigned u = __float_as_uint(s);
    u ^= (unsigned)((int)u >> 31) | 0x80000000u;
    return ((unsigned long long)u << 13) | (unsigned)c;
}

// Z (A-operand) 16 KB tile: (row 0..127, dloc 0..63 f16), slot = (dloc>>3) ^ (row&7)
__device__ __forceinline__ int swz_off(int row, int dloc) {
    return row * 128 + ((((dloc >> 3) ^ (row & 7))) << 4) + ((dloc & 7) << 1);
}

__device__ __forceinline__ void gload16(const void* g, void* l) {
    __builtin_amdgcn_global_load_lds((const __attribute__((address_space(1))) unsigned int*)g,
                                     (__attribute__((address_space(3))) unsigned int*)l,
                                     16, 0, 0);
}

// ---------------- kernel 0: fp32 -> fp16 pre-tiled+swizzled, fused codebook norms ----------------
// Z: 16 KB tiles (128 rows x 64 d), slot = (dloc>>3) ^ (row&7)
// E: 8 KB tiles  (128 cols x 32 d), slot = (dloc>>3) ^ ((col>>1)&3)   [BK=32 stage chunks]
__global__ __launch_bounds__(256) void convert_kernel(const float* __restrict__ Z,
                                                      const float* __restrict__ E,
                                                      char* __restrict__ ws) {
    const int t  = threadIdx.x;
    const int r  = blockIdx.x * 4 + (t >> 6);   // one wave per row
    const int d0 = (t & 63) * 4;
    const float* src;
    char* dh;
    const bool isE = (r >= N_VEC);
    if (!isE) {
        src = Z + (size_t)r * D_DIM;
        const int rowl = r & 127;
        dh = ws + WS_ZH + (size_t)(((r >> 7) * 4) + (d0 >> 6)) * 16384
           + swz_off(rowl, d0 & 63);
    } else {
        const int re = r - N_VEC;
        src = E + (size_t)re * D_DIM;
        const int col  = re & 127;
        const int k32  = d0 >> 5;          // 0..7
        const int dloc = d0 & 31;
        const int slot = (dloc >> 3) ^ ((col >> 1) & 3);
        dh = ws + WS_EH + (size_t)((re >> 7) * 8 + k32) * 8192
           + col * 64 + slot * 16 + (dloc & 7) * 2;
    }
    const float4 v = *reinterpret_cast<const float4*>(src + d0);
    const unsigned h0 = __half_as_ushort(__float2half(v.x));
    const unsigned h1 = __half_as_ushort(__float2half(v.y));
    const unsigned h2 = __half_as_ushort(__float2half(v.z));
    const unsigned h3 = __half_as_ushort(__float2half(v.w));
    uint2 hi;
    hi.x = h0 | (h1 << 16);  hi.y = h2 | (h3 << 16);
    *reinterpret_cast<uint2*>(dh) = hi;

    if (isE) {   // fused ||e||^2 (fp32, exact same reduction as all passing rounds)
        float s = v.x * v.x + v.y * v.y + v.z * v.z + v.w * v.w;
        #pragma unroll
        for (int off = 32; off; off >>= 1) s += __shfl_down(s, off);
        if ((t & 63) == 0) ((float*)(ws + WS_ENORM))[r - N_VEC] = s;
    }
}

// ---------------- kernel 1: fp16 MFMA screen (r12-exact, best measured 84.5 us):
//   A static in LDS, B dbuf 8 KB chunks; single-barrier phase: vmcnt(0) ->
//   s_barrier -> { ds_read | STAGE next | MFMA } compiler-interleaved. ----------------
__global__ __launch_bounds__(256, 2) void vq_mfma_kernel(const char* __restrict__ ws_ro,
                                                         ulonglong2* __restrict__ part2) {
    __shared__ short lds[40960];   // A: [0,32768) shorts (64 KB); B dbuf: [32768,40960) (16 KB)

    const int tid  = threadIdx.x;
    const int lane = tid & 63, wid = tid >> 6;
    const int lane15 = lane & 15, g = lane >> 4;
    const int l7  = lane15 & 7;
    const int c13 = (lane15 >> 1) & 3;
    const int wm = wid >> 1, wn = wid & 1;
    const int bx = blockIdx.x, ksp = blockIdx.y;
    const int row0 = bx * BM;
    const int kbase = ksp * (K_CODES / NSPLIT);

    const char* zh = ws_ro + WS_ZH;
    const char* eh = ws_ro + WS_EH;
    const float* enorm = (const float*)(ws_ro + WS_ENORM);

    #define STAGE_B(kt_, j_)                                                           \
    do {                                                                               \
        const char* sB = eh + (size_t)(((ksp * 8 + (kt_)) * 8) + (j_)) * 8192          \
                            + wid * 2048 + lane * 16;                                  \
        short* dB = lds + 32768 + ((j_) & 1) * 4096 + wid * 1024 + lane * 8;           \
        gload16(sB, dB);                                                               \
        gload16(sB + 1024, dB + 512);                                                  \
    } while (0)

    {
        const char* srcA = zh + (size_t)bx * 65536 + wid * 16384 + lane * 16;
        short* dA = lds + wid * 8192 + lane * 8;
        #pragma unroll
        for (int i = 0; i < 16; ++i) gload16(srcA + i * 1024, dA + i * 512);
    }
    STAGE_B(0, 0);
    float en_c[4], en_n[4];
    #pragma unroll
    for (int n = 0; n < 4; ++n) en_c[n] = enorm[kbase + wn * 64 + n * 16 + lane15];
    asm volatile("s_waitcnt vmcnt(0)" ::: "memory");
    __builtin_amdgcn_s_barrier();
    __builtin_amdgcn_sched_barrier(0);

    int rowterm[4];
    #pragma unroll
    for (int m = 0; m < 4; ++m) rowterm[m] = (wm * 64 + m * 16 + lane15) * 64;
    int colterm[4];
    #pragma unroll
    for (int n = 0; n < 4; ++n) colterm[n] = (wn * 64 + n * 16 + lane15) * 32;
    const int sa0 = (g ^ l7) * 8;
    const int sb  = (g ^ c13) * 8;

    float bestv[16];
    int   bestc[16];
    #pragma unroll
    for (int i = 0; i < 16; ++i) { bestv[i] = 3.0e38f; bestc[i] = 0; }

    #define STEP(j_)                                                                   \
    do {                                                                               \
        asm volatile("s_waitcnt vmcnt(0)" ::: "memory");                               \
        __builtin_amdgcn_s_barrier();                                                  \
        __builtin_amdgcn_sched_barrier(0);                                             \
        f16x8 af[4], bf[4];                                                            \
        const int abase = ((j_) >> 1) * 8192 + (sa0 ^ (((j_) & 1) << 5));              \
        const int bbase = 32768 + ((j_) & 1) * 4096 + sb;                              \
        _Pragma("unroll")                                                              \
        for (int m = 0; m < 4; ++m)                                                    \
            af[m] = *reinterpret_cast<const f16x8*>(lds + abase + rowterm[m]);         \
        _Pragma("unroll")                                                              \
        for (int n = 0; n < 4; ++n)                                                    \
            bf[n] = *reinterpret_cast<const f16x8*>(lds + bbase + colterm[n]);         \
        if ((j_) < 7) {                                                                \
            STAGE_B(kt, (j_) + 1);                                                     \
        } else if (kt < KT_PER - 1) {                                                  \
            STAGE_B(kt + 1, 0);                                                        \
            _Pragma("unroll")                                                          \
            for (int n = 0; n < 4; ++n)                                                \
                en_n[n] = enorm[kbase + (kt + 1) * 128 + wn * 64 + n * 16 + lane15];   \
        }                                                                              \
        __builtin_amdgcn_s_setprio(1);                                                 \
        _Pragma("unroll")                                                              \
        for (int m = 0; m < 4; ++m)                                                    \
            _Pragma("unroll")                                                          \
            for (int n = 0; n < 4; ++n)                                                \
                acc[m][n] = __builtin_amdgcn_mfma_f32_16x16x32_f16(                    \
                    af[m], bf[n], acc[m][n], 0, 0, 0);                                 \
        __builtin_amdgcn_s_setprio(0);                                                 \
    } while (0)

    for (int kt = 0; kt < KT_PER; ++kt) {
        f32x4 acc[4][4];
        #pragma unroll
        for (int m = 0; m < 4; ++m)
            #pragma unroll
            for (int n = 0; n < 4; ++n)
                #pragma unroll
                for (int q = 0; q < 4; ++q) acc[m][n][q] = 0.0f;

        STEP(0); STEP(1); STEP(2); STEP(3);
        STEP(4); STEP(5); STEP(6); STEP(7);

        #pragma unroll
        for (int m = 0; m < 4; ++m)
            #pragma unroll
            for (int n = 0; n < 4; ++n) {
                const int c = kbase + kt * 128 + wn * 64 + n * 16 + lane15;
                #pragma unroll
                for (int q = 0; q < 4; ++q) {
                    const int sl = m * 4 + q;
                    const float s = fmaf(-2.0f, acc[m][n][q], en_c[n]);
                    if (s < bestv[sl]) { bestv[sl] = s; bestc[sl] = c; }
                }
            }
        #pragma unroll
        for (int n = 0; n < 4; ++n) en_c[n] = en_n[n];
    }
    #undef STEP
    #undef STAGE_B

    // tail: per-row top-2 over the 16 lanes sharing each row (lexicographic keys)
    unsigned long long* t2 = reinterpret_cast<unsigned long long*>(lds);  // [wid][64][2]
    #pragma unroll
    for (int sl = 0; sl < 16; ++sl) {
        const int m = sl >> 2, q = sl & 3;
        const unsigned long long k1 = skey(bestv[sl], bestc[sl]);
        unsigned long long m1 = k1;
        #pragma unroll
        for (int msk = 1; msk < 16; msk <<= 1) {
            const unsigned long long o = __shfl_xor(m1, msk);
            m1 = (o < m1) ? o : m1;
        }
        unsigned long long k2 = (k1 == m1) ? ~0ull : k1;
        #pragma unroll
        for (int msk = 1; msk < 16; msk <<= 1) {
            const unsigned long long o = __shfl_xor(k2, msk);
            k2 = (o < k2) ? o : k2;
        }
        if (lane15 == 0) {
            const int row64 = m * 16 + g * 4 + q;
            t2[(wid * 64 + row64) * 2 + 0] = m1;
            t2[(wid * 64 + row64) * 2 + 1] = k2;
        }
    }
    __syncthreads();
    if (tid < 128) {
        const int wm2 = tid >> 6, r64 = tid & 63;
        const unsigned long long a1 = t2[((wm2 * 2 + 0) * 64 + r64) * 2 + 0];
        const unsigned long long a2 = t2[((wm2 * 2 + 0) * 64 + r64) * 2 + 1];
        const unsigned long long b1 = t2[((wm2 * 2 + 1) * 64 + r64) * 2 + 0];
        const unsigned long long b2 = t2[((wm2 * 2 + 1) * 64 + r64) * 2 + 1];
        const unsigned long long r1 = (a1 < b1) ? a1 : b1;
        const unsigned long long hi = (a1 < b1) ? b1 : a1;
        const unsigned long long l2 = (a2 < b2) ? a2 : b2;
        const unsigned long long r2 = (hi < l2) ? hi : l2;
        ulonglong2 res;  res.x = r1;  res.y = r2;
        part2[(size_t)ksp * N_VEC + row0 + tid] = res;
    }
}

// ---------------- kernel 2: merge splits + exact fp64 rescore of global top-4 + loss ----------------
__global__ __launch_bounds__(256) void rescore_kernel(const float* __restrict__ Z,
                                                      const float* __restrict__ E,
                                                      const ulonglong2* __restrict__ part2,
                                                      int* __restrict__ idx_i,
                                                      float* __restrict__ out_idx,
                                                      float* __restrict__ lossp) {
    __shared__ double redl[4];
    const int tid = threadIdx.x, lane = tid & 63, wid = tid >> 6;
    const int r = blockIdx.x * 4 + wid;
    int c0 = 0, c1 = 0, c2 = 0, c3 = 0;
    if (lane == 0) {
        unsigned long long m0 = ~0ull, m1 = ~0ull, m2 = ~0ull, m3 = ~0ull;
        for (int s = 0; s < NSPLIT; ++s) {
            const ulonglong2 p = part2[(size_t)s * N_VEC + r];
            unsigned long long k = p.x;
            if (k < m0) { m3 = m2; m2 = m1; m1 = m0; m0 = k; }
            else if (k < m1) { m3 = m2; m2 = m1; m1 = k; }
            else if (k < m2) { m3 = m2; m2 = k; }
            else if (k < m3) { m3 = k; }
            k = p.y;
            if (k < m0) { m3 = m2; m2 = m1; m1 = m0; m0 = k; }
            else if (k < m1) { m3 = m2; m2 = m1; m1 = k; }
            else if (k < m2) { m3 = m2; m2 = k; }
            else if (k < m3) { m3 = k; }
        }
        c0 = (int)(m0 & 0x1FFFull);  c1 = (int)(m1 & 0x1FFFull);
        c2 = (int)(m2 & 0x1FFFull);  c3 = (int)(m3 & 0x1FFFull);
    }
    c0 = __shfl(c0, 0);  c1 = __shfl(c1, 0);
    c2 = __shfl(c2, 0);  c3 = __shfl(c3, 0);
    const float4 z4 = *reinterpret_cast<const float4*>(Z + (size_t)r * D_DIM + lane * 4);
    double d[4];
    const int cc[4] = {c0, c1, c2, c3};
    #pragma unroll
    for (int j = 0; j < 4; ++j) {
        const float4 e4 = *reinterpret_cast<const float4*>(E + (size_t)cc[j] * D_DIM + lane * 4);
        const double ax = (double)z4.x - (double)e4.x, ay = (double)z4.y - (double)e4.y;
        const double az = (double)z4.z - (double)e4.z, aw = (double)z4.w - (double)e4.w;
        d[j] = ax * ax + ay * ay + az * az + aw * aw;
    }
    #pragma unroll
    for (int off = 1; off < 64; off <<= 1) {
        #pragma unroll
        for (int j = 0; j < 4; ++j) d[j] += __shfl_xor(d[j], off);
    }
    if (lane == 0) {
        double bd = d[0];  int bi = c0;
        #pragma unroll
        for (int j = 1; j < 4; ++j) {
            if (d[j] < bd || (d[j] == bd && cc[j] < bi)) { bd = d[j]; bi = cc[j]; }
        }
        idx_i[r]   = bi;
        out_idx[r] = (float)bi;
        redl[wid]  = bd;            // exact ||z - zq||^2 of the chosen code
    }
    __syncthreads();
    if (tid == 0) lossp[blockIdx.x] = (float)(redl[0] + redl[1] + redl[2] + redl[3]);
}

// ---------------- kernel 3: gather + NCHW transpose ----------------
__global__ __launch_bounds__(256) void gather_kernel(const float* __restrict__ E,
                                                     const int* __restrict__ idx_i,
                                                     float* __restrict__ out) {
    __shared__ float Ls[128 * 65];
    __shared__ int   sIdx[64];

    const int tid = threadIdx.x;
    const int gb  = blockIdx.x;       // 0..255, 64 latent vectors each
    const int n0  = gb * 64;
    const int b   = n0 >> 10;
    const int hwbase = n0 & 1023;

    if (tid < 64) sIdx[tid] = idx_i[n0 + tid];
    __syncthreads();

    for (int h = 0; h < 2; ++h) {
        if (h) __syncthreads();
        const int rowl = tid >> 2;
        const int qs   = tid & 3;
        const float* erow = E + (size_t)sIdx[rowl] * D_DIM + h * 128;
        #pragma unroll
        for (int m = 0; m < 8; ++m) {
            const int c4 = m * 4 + qs;
            const float4 v = *reinterpret_cast<const float4*>(erow + c4 * 4);
            Ls[(c4 * 4 + 0) * 65 + rowl] = v.x;
            Ls[(c4 * 4 + 1) * 65 + rowl] = v.y;
            Ls[(c4 * 4 + 2) * 65 + rowl] = v.z;
            Ls[(c4 * 4 + 3) * 65 + rowl] = v.w;
        }
        __syncthreads();
        const int wl   = tid & 63;
        const int csub = tid >> 6;
        #pragma unroll
        for (int pc = 0; pc < 32; ++pc) {
            const int c_l = pc * 4 + csub;
            const int c   = h * 128 + c_l;
            out[((size_t)(b * 256 + c)) * 1024 + hwbase + wl] = Ls[c_l * 65 + wl];
        }
    }
}

// ---------------- kernel 4: finalize scalars ----------------
__global__ __launch_bounds__(256) void final_kernel(const float* __restrict__ lossp,
                                                    float* __restrict__ out) {
    __shared__ float red[4];
    const int tid = threadIdx.x;
    float s = 0.0f;
    for (int i = tid; i < N_VEC / 4; i += 256) s += lossp[i];
    #pragma unroll
    for (int off = 32; off; off >>= 1) s += __shfl_down(s, off);
    if ((tid & 63) == 0) red[tid >> 6] = s;
    __syncthreads();
    if (tid == 0) {
        const float total = red[0] + red[1] + red[2] + red[3];
        out[DIFF_OFF] = 0.25f * (total / (float)(N_VEC * D_DIM));
        out[PERP_OFF] = 1.0f;
    }
}

// ---------------- launcher ----------------
extern "C" void kernel_launch(void* const* d_in, const int* in_sizes, int n_in,
                              void* d_out, int out_size, void* d_ws, size_t ws_size,
                              hipStream_t stream) {
    const float* Z = (const float*)d_in[0];   // (16,32,32,256) fp32
    const float* E = (const float*)d_in[1];   // (8192,256) fp32
    float* out = (float*)d_out;
    char*  ws  = (char*)d_ws;                 // needs ~14.6 MB

    ulonglong2* part2   = (ulonglong2*)(ws + WS_P2);
    int*        idx_i   = (int*)(ws + WS_IDXI);
    float*      lossbuf = (float*)(ws + WS_LOSS);

    hipLaunchKernelGGL(convert_kernel, dim3((N_VEC + K_CODES) / 4), dim3(256), 0, stream, Z, E, ws);
    hipLaunchKernelGGL(vq_mfma_kernel, dim3(N_VEC / BM, NSPLIT), dim3(256), 0, stream,
                       (const char*)ws, part2);
    hipLaunchKernelGGL(rescore_kernel, dim3(N_VEC / 4), dim3(256), 0, stream,
                       Z, E, part2, idx_i, out + IDX_OFF, lossbuf);
    hipLaunchKernelGGL(gather_kernel, dim3(N_VEC / 64), dim3(256), 0, stream,
                       E, idx_i, out);
    hipLaunchKernelGGL(final_kernel, dim3(1), dim3(256), 0, stream, lossbuf, out);
}